// Round 2
// baseline (110.190 us; speedup 1.0000x reference)
//
#include <hip/hip_runtime.h>

// Proximity: mean over B of clipped L2 distance between L2-normalized x row
// and its label's L2-normalized center row.
// dist[i] = sxx/nx^2 + scc/nc^2 - 2*sxc/(nx*nc),  n* = max(sqrt(s**), eps)

#define EPS_MIN 1e-12f
#define CLAMP_MAX 1e12f

typedef float v4f __attribute__((ext_vector_type(4)));

// One wave (64 lanes) per sample; 4 waves/block; per-wave partial write,
// no LDS, no __syncthreads.
__global__ __launch_bounds__(256) void prox_partial_kernel(
    const float* __restrict__ x,
    const int* __restrict__ labels,
    const float* __restrict__ centers,
    float* __restrict__ partial,
    int Bn, int Dn)
{
    const int wave = threadIdx.x >> 6;
    const int lane = threadIdx.x & 63;
    const int sample = blockIdx.x * 4 + wave;
    if (sample >= Bn) return;

    const v4f* __restrict__ xr =
        (const v4f*)(x + (size_t)sample * Dn);
    const v4f* __restrict__ cr =
        (const v4f*)(centers + (size_t)labels[sample] * Dn);

    const int nf4 = Dn >> 2;                // 256 float4s per row
    float sxx = 0.f, scc = 0.f, sxc = 0.f;
    for (int i = lane; i < nf4; i += 64) {
        // x is streamed exactly once: nontemporal, don't evict centers from L2.
        v4f xv = __builtin_nontemporal_load(xr + i);
        v4f cv = cr[i];                     // centers: cached (16x reuse)
        sxx += xv.x * xv.x + xv.y * xv.y + xv.z * xv.z + xv.w * xv.w;
        scc += cv.x * cv.x + cv.y * cv.y + cv.z * cv.z + cv.w * cv.w;
        sxc += xv.x * cv.x + xv.y * cv.y + xv.z * cv.z + xv.w * cv.w;
    }
    // 64-lane butterfly
    #pragma unroll
    for (int off = 32; off > 0; off >>= 1) {
        sxx += __shfl_down(sxx, off, 64);
        scc += __shfl_down(scc, off, 64);
        sxc += __shfl_down(sxc, off, 64);
    }
    if (lane == 0) {
        float nx = fmaxf(sqrtf(sxx), EPS_MIN);
        float nc = fmaxf(sqrtf(scc), EPS_MIN);
        float d = sxx / (nx * nx) + scc / (nc * nc) - 2.0f * (sxc / (nx * nc));
        d = fminf(fmaxf(d, EPS_MIN), CLAMP_MAX);
        partial[sample] = d;                // one float per wave, coalesced-ish
    }
}

// Single-block deterministic reduction of Bn partials -> mean.
__global__ __launch_bounds__(1024) void prox_final_kernel(
    const float* __restrict__ partial, float* __restrict__ out,
    int n, float inv_B)
{
    float s = 0.f;
    for (int i = threadIdx.x; i < n; i += 1024) s += partial[i];

    __shared__ float smem[16];
    #pragma unroll
    for (int off = 32; off > 0; off >>= 1) s += __shfl_down(s, off, 64);
    const int wave = threadIdx.x >> 6;
    const int lane = threadIdx.x & 63;
    if (lane == 0) smem[wave] = s;
    __syncthreads();
    if (threadIdx.x == 0) {
        float t = 0.f;
        #pragma unroll
        for (int w = 0; w < 16; ++w) t += smem[w];
        out[0] = t * inv_B;
    }
}

extern "C" void kernel_launch(void* const* d_in, const int* in_sizes, int n_in,
                              void* d_out, int out_size, void* d_ws, size_t ws_size,
                              hipStream_t stream)
{
    const float* x       = (const float*)d_in[0];
    const int*   labels  = (const int*)d_in[1];
    const float* centers = (const float*)d_in[2];
    float* out = (float*)d_out;

    const int Bn = in_sizes[1];            // 16384
    const int Dn = in_sizes[0] / Bn;       // 1024

    const int blocks = (Bn + 3) / 4;       // 4096 blocks, 1 sample per wave
    float* partial = (float*)d_ws;         // Bn * 4 bytes <= ws_size

    prox_partial_kernel<<<blocks, 256, 0, stream>>>(x, labels, centers,
                                                    partial, Bn, Dn);
    prox_final_kernel<<<1, 1024, 0, stream>>>(partial, out, Bn,
                                              1.0f / (float)Bn);
}

// Round 3
// 104.380 us; speedup vs baseline: 1.0557x; 1.0557x over previous
//
#include <hip/hip_runtime.h>

// Proximity: mean over B of clipped L2 distance between L2-normalized x row
// and its label's L2-normalized center row.
// dist[i] = sxx/nx^2 + scc/nc^2 - 2*sxc/(nx*nc),  n* = max(sqrt(s**), eps)

#define EPS_MIN 1e-12f
#define CLAMP_MAX 1e12f

typedef float v4f __attribute__((ext_vector_type(4)));

// One wave (64 lanes) per sample; 4 waves/block; per-wave partial write,
// no LDS, no __syncthreads. Plain (cached) loads: NT loads regressed R2
// (103.5 -> 110.2 us) — x stream coalesces better through L2.
__global__ __launch_bounds__(256) void prox_partial_kernel(
    const float* __restrict__ x,
    const int* __restrict__ labels,
    const float* __restrict__ centers,
    float* __restrict__ partial,
    int Bn, int Dn)
{
    const int wave = threadIdx.x >> 6;
    const int lane = threadIdx.x & 63;
    const int sample = blockIdx.x * 4 + wave;
    if (sample >= Bn) return;

    const v4f* __restrict__ xr = (const v4f*)(x + (size_t)sample * Dn);
    const v4f* __restrict__ cr = (const v4f*)(centers + (size_t)labels[sample] * Dn);

    const int nf4 = Dn >> 2;                // 256 float4s per row (D=1024)
    float sxx = 0.f, scc = 0.f, sxc = 0.f;
    // 4 iterations for D=1024: unroll fully so 8 loads are in flight per lane.
    #pragma unroll 4
    for (int i = lane; i < nf4; i += 64) {
        v4f xv = xr[i];
        v4f cv = cr[i];
        sxx += xv.x * xv.x + xv.y * xv.y + xv.z * xv.z + xv.w * xv.w;
        scc += cv.x * cv.x + cv.y * cv.y + cv.z * cv.z + cv.w * cv.w;
        sxc += xv.x * cv.x + xv.y * cv.y + xv.z * cv.z + xv.w * cv.w;
    }
    // 64-lane butterfly
    #pragma unroll
    for (int off = 32; off > 0; off >>= 1) {
        sxx += __shfl_down(sxx, off, 64);
        scc += __shfl_down(scc, off, 64);
        sxc += __shfl_down(sxc, off, 64);
    }
    if (lane == 0) {
        float nx = fmaxf(sqrtf(sxx), EPS_MIN);
        float nc = fmaxf(sqrtf(scc), EPS_MIN);
        float d = sxx / (nx * nx) + scc / (nc * nc) - 2.0f * (sxc / (nx * nc));
        d = fminf(fmaxf(d, EPS_MIN), CLAMP_MAX);
        partial[sample] = d;
    }
}

// Single-block deterministic reduction of Bn partials -> mean.
__global__ __launch_bounds__(1024) void prox_final_kernel(
    const float* __restrict__ partial, float* __restrict__ out,
    int n, float inv_B)
{
    float s = 0.f;
    for (int i = threadIdx.x; i < n; i += 1024) s += partial[i];

    __shared__ float smem[16];
    #pragma unroll
    for (int off = 32; off > 0; off >>= 1) s += __shfl_down(s, off, 64);
    const int wave = threadIdx.x >> 6;
    const int lane = threadIdx.x & 63;
    if (lane == 0) smem[wave] = s;
    __syncthreads();
    if (threadIdx.x == 0) {
        float t = 0.f;
        #pragma unroll
        for (int w = 0; w < 16; ++w) t += smem[w];
        out[0] = t * inv_B;
    }
}

extern "C" void kernel_launch(void* const* d_in, const int* in_sizes, int n_in,
                              void* d_out, int out_size, void* d_ws, size_t ws_size,
                              hipStream_t stream)
{
    const float* x       = (const float*)d_in[0];
    const int*   labels  = (const int*)d_in[1];
    const float* centers = (const float*)d_in[2];
    float* out = (float*)d_out;

    const int Bn = in_sizes[1];            // 16384
    const int Dn = in_sizes[0] / Bn;       // 1024

    const int blocks = (Bn + 3) / 4;       // 4096 blocks, 1 sample per wave
    float* partial = (float*)d_ws;         // Bn * 4 bytes <= ws_size

    prox_partial_kernel<<<blocks, 256, 0, stream>>>(x, labels, centers,
                                                    partial, Bn, Dn);
    prox_final_kernel<<<1, 1024, 0, stream>>>(partial, out, Bn,
                                              1.0f / (float)Bn);
}